// Round 6
// baseline (228.685 us; speedup 1.0000x reference)
//
#include <hip/hip_runtime.h>

#define T_LEN 512
#define NHID 16
#define NEMB 10
#define VOCAB1 50001
#define ISTR 521   // idx row stride (ints): 521%32=9 -> 8 broadcast reads hit 8 banks

typedef float v2f __attribute__((ext_vector_type(2)));

// ---------------------------------------------------------------------------
// Kernel 1: xproj table, layout [v][16][4] f32: float4 at (v*16+j) =
//   {i,f,g,o} pre-activations for unit j = bih+bhh + emb[v]·Wih rows.
// ---------------------------------------------------------------------------
__global__ __launch_bounds__(256) void build_table(
    const float* __restrict__ emb, const float* __restrict__ Wih,
    const float* __restrict__ bih, const float* __restrict__ bhh,
    float* __restrict__ tbl)
{
    const int tid = blockIdx.x * 256 + threadIdx.x;
    if (tid >= VOCAB1 * 16) return;
    const int v = tid >> 4, j = tid & 15;
    float e[NEMB];
    #pragma unroll
    for (int i = 0; i < NEMB; ++i) e[i] = emb[v * NEMB + i];
    float o[4];
    #pragma unroll
    for (int q = 0; q < 4; ++q) {
        const int r = q * 16 + j;
        float a = bih[r] + bhh[r];
        #pragma unroll
        for (int i = 0; i < NEMB; ++i) a += e[i] * Wih[r * NEMB + i];
        o[q] = a;
    }
    ((float4*)tbl)[tid] = make_float4(o[0], o[1], o[2], o[3]);
}

// ---------------------------------------------------------------------------
// Kernel 2: 16 lanes/batch, ILP=2. One wave per 64-thread block, 8 batches
// per wave (chains A: groups 0..3, B: groups 4..7 of hx). 512 blocks ->
// 2 blocks/CU on all 256 CUs. Everything wave-private: NO __syncthreads.
// Per chain: 4-stage compile-time-indexed table-load pipeline (R5 scheme,
// counted vmcnt, 8 loads in flight across both chains). B's gate compute
// sits between A's LDS h-write and h-readback, hiding the LDS round trip.
// Token indices pre-scaled x16 in LDS (stride-521 rows: conflict-free).
// ---------------------------------------------------------------------------
__global__ __launch_bounds__(64) void lstm_ilp2p_kernel(
    const int*   __restrict__ x,
    const float* __restrict__ tbl,
    const float* __restrict__ Whh,
    const float* __restrict__ Wfc,
    const float* __restrict__ bfc,
    float*       __restrict__ out)
{
    __shared__ int   idxs[8 * ISTR];   // [batch][t] token*16, 16.7 KB
    __shared__ float hx[8 * 16];       // [batch][unit] h exchange, 512 B

    const int lane = threadIdx.x;      // 0..63
    const int j    = lane & 15;        // hidden unit owned
    const int g    = lane >> 4;        // group 0..3
    const int lbA  = g;                // chain-A local batch
    const int lbB  = g + 4;            // chain-B local batch
    const int base = blockIdx.x * 8;
    const int bA   = base + lbA;
    const int bB   = base + lbB;

    // stage token indices (pre-scaled by 16 = float4-row offset), per-wave
    #pragma unroll 1
    for (int b = 0; b < 8; ++b) {
        const int* xr = x + (long)(base + b) * T_LEN;
        for (int tt = lane; tt < ISTR; tt += 64)
            idxs[b * ISTR + tt] = (tt < T_LEN) ? (xr[tt] << 4) : 0;
    }

    // recurrent weights: 4 gate rows for unit j as float2 pairs (pk_fma)
    v2f w[4][8];
    #pragma unroll
    for (int q = 0; q < 4; ++q) {
        const int r = j + 16 * q;
        #pragma unroll
        for (int p = 0; p < 8; ++p)
            w[q][p] = (v2f){Whh[r * NHID + 2 * p], Whh[r * NHID + 2 * p + 1]};
    }

    v2f hA[8], hB[8];
    #pragma unroll
    for (int p = 0; p < 8; ++p) { hA[p] = (v2f){0.f, 0.f}; hB[p] = (v2f){0.f, 0.f}; }
    float cA = 0.f, cB = 0.f;

    const float NL2E  = -1.44269504088896f;
    const float NL2E2 = -2.88539008177793f;
    const float4* t4  = (const float4*)tbl;
    const float4* hpA = (const float4*)&hx[lbA * 16];
    const float4* hpB = (const float4*)&hx[lbB * 16];
    const int iA = lbA * ISTR, iB = lbB * ISTR;

    // one LSTM step (bit-identical math to R2/R5)
    auto step = [&](const float4& tb, v2f* h2, float& c) -> float {
        v2f a0 = (v2f){tb.x, 0.f}, a1 = (v2f){tb.y, 0.f};
        v2f a2 = (v2f){tb.z, 0.f}, a3 = (v2f){tb.w, 0.f};
        #pragma unroll
        for (int p = 0; p < 8; ++p) {
            a0 += h2[p] * w[0][p];
            a1 += h2[p] * w[1][p];
            a2 += h2[p] * w[2][p];
            a3 += h2[p] * w[3][p];
        }
        const float vi = a0.x + a0.y, vf = a1.x + a1.y;
        const float vg = a2.x + a2.y, vo = a3.x + a3.y;
        const float ig = __builtin_amdgcn_rcpf(1.f + __builtin_amdgcn_exp2f(vi * NL2E));
        const float fg = __builtin_amdgcn_rcpf(1.f + __builtin_amdgcn_exp2f(vf * NL2E));
        const float gg = 2.f * __builtin_amdgcn_rcpf(1.f + __builtin_amdgcn_exp2f(vg * NL2E2)) - 1.f;
        const float og = __builtin_amdgcn_rcpf(1.f + __builtin_amdgcn_exp2f(vo * NL2E));
        c = fg * c + ig * gg;
        const float tc = 2.f * __builtin_amdgcn_rcpf(1.f + __builtin_amdgcn_exp2f(c * NL2E2)) - 1.f;
        return og * tc;
    };

    // prologue: fill both 4-stage pipelines (rows for t = 0..3)
    float4 pfA[4], pfB[4];
    #pragma unroll
    for (int s = 0; s < 4; ++s) {
        pfA[s] = t4[(long)(idxs[iA + s] + j)];
        pfB[s] = t4[(long)(idxs[iB + s] + j)];
    }

    #pragma unroll 1
    for (int t = 0; t < T_LEN; t += 4) {
        #pragma unroll
        for (int u = 0; u < 4; ++u) {
            const float4 tbA = pfA[u];               // counted vmcnt wait
            const float4 tbB = pfB[u];
            // refill stage u with rows for t+4+u (stays in flight 4 steps)
            pfA[u] = t4[(long)(idxs[iA + t + 4 + u] + j)];
            pfB[u] = t4[(long)(idxs[iB + t + 4 + u] + j)];

            // chain A step + h-write; chain B's compute hides A's LDS RT
            const float hvA = step(tbA, hA, cA);
            hx[lbA * 16 + j] = hvA;

            const float hvB = step(tbB, hB, cB);
            hx[lbB * 16 + j] = hvB;

            // readbacks (wave-private, in-order DS completion)
            const float4 a0 = hpA[0], a1 = hpA[1], a2 = hpA[2], a3 = hpA[3];
            const float4 b0 = hpB[0], b1 = hpB[1], b2 = hpB[2], b3 = hpB[3];
            hA[0] = (v2f){a0.x, a0.y}; hA[1] = (v2f){a0.z, a0.w};
            hA[2] = (v2f){a1.x, a1.y}; hA[3] = (v2f){a1.z, a1.w};
            hA[4] = (v2f){a2.x, a2.y}; hA[5] = (v2f){a2.z, a2.w};
            hA[6] = (v2f){a3.x, a3.y}; hA[7] = (v2f){a3.z, a3.w};
            hB[0] = (v2f){b0.x, b0.y}; hB[1] = (v2f){b0.z, b0.w};
            hB[2] = (v2f){b1.x, b1.y}; hB[3] = (v2f){b1.z, b1.w};
            hB[4] = (v2f){b2.x, b2.y}; hB[5] = (v2f){b2.z, b2.w};
            hB[6] = (v2f){b3.x, b3.y}; hB[7] = (v2f){b3.z, b3.w};
        }
    }

    if (j == 0) {
        float lgA = bfc[0], lgB = bfc[0];
        #pragma unroll
        for (int p = 0; p < 8; ++p) {
            lgA += hA[p].x * Wfc[2 * p] + hA[p].y * Wfc[2 * p + 1];
            lgB += hB[p].x * Wfc[2 * p] + hB[p].y * Wfc[2 * p + 1];
        }
        out[bA] = __builtin_amdgcn_rcpf(1.f + __builtin_amdgcn_exp2f(lgA * NL2E));
        out[bB] = __builtin_amdgcn_rcpf(1.f + __builtin_amdgcn_exp2f(lgB * NL2E));
    }
}

// ---------------------------------------------------------------------------
// Fallback (ws too small for the 12.8 MB table): on-the-fly xproj path.
// ---------------------------------------------------------------------------
__global__ __launch_bounds__(256) void lstm_fb_kernel(
    const int*   __restrict__ x,
    const float* __restrict__ emb,
    const float* __restrict__ Wih,
    const float* __restrict__ Whh,
    const float* __restrict__ bih,
    const float* __restrict__ bhh,
    const float* __restrict__ Wfc,
    const float* __restrict__ bfc,
    float*       __restrict__ out)
{
    __shared__ int   idx_lds[T_LEN][17];
    __shared__ float hx[16][20];

    const int tid  = threadIdx.x;
    const int lane = tid & 63;
    const int j    = lane & 15;
    const int lb   = tid >> 4;
    const int batch = blockIdx.x * 16 + lb;

    for (int i = tid; i < 16 * T_LEN; i += 256) {
        const int b = i & 15;
        const int t = i >> 4;
        idx_lds[t][b] = x[(blockIdx.x * 16 + b) * T_LEN + t];
    }

    float wih[4][NEMB], bias[4];
    v2f w[4][8];
    #pragma unroll
    for (int q = 0; q < 4; ++q) {
        const int r = j + 16 * q;
        #pragma unroll
        for (int e = 0; e < NEMB; ++e) wih[q][e] = Wih[r * NEMB + e];
        #pragma unroll
        for (int p = 0; p < 8; ++p)
            w[q][p] = (v2f){Whh[r * NHID + 2 * p], Whh[r * NHID + 2 * p + 1]};
        bias[q] = bih[r] + bhh[r];
    }

    __syncthreads();

    v2f h2[8];
    #pragma unroll
    for (int p = 0; p < 8; ++p) h2[p] = (v2f){0.f, 0.f};
    float c = 0.f;

    const float NL2E  = -1.44269504088896f;
    const float NL2E2 = -2.88539008177793f;
    const float4* hp = (const float4*)&hx[lb][0];

    float2 xa, xb, xc, xd, xe2;
    {
        const float2* er = (const float2*)(emb + (long)idx_lds[0][lb] * NEMB);
        xa = er[0]; xb = er[1]; xc = er[2]; xd = er[3]; xe2 = er[4];
    }
    int idx_n = idx_lds[1][lb];

    #pragma unroll 1
    for (int t = 0; t < T_LEN; ++t) {
        const float xv[NEMB] = {xa.x, xa.y, xb.x, xb.y, xc.x, xc.y,
                                xd.x, xd.y, xe2.x, xe2.y};
        if (t + 1 < T_LEN) {
            const float2* er = (const float2*)(emb + (long)idx_n * NEMB);
            xa = er[0]; xb = er[1]; xc = er[2]; xd = er[3]; xe2 = er[4];
        }
        const int idx_nn = (t + 2 < T_LEN) ? idx_lds[t + 2][lb] : 0;

        float v[4];
        #pragma unroll
        for (int q = 0; q < 4; ++q) {
            float a = bias[q];
            #pragma unroll
            for (int e = 0; e < NEMB; ++e) a += xv[e] * wih[q][e];
            v[q] = a;
        }
        v2f a0 = (v2f){v[0], 0.f}, a1 = (v2f){v[1], 0.f};
        v2f a2 = (v2f){v[2], 0.f}, a3 = (v2f){v[3], 0.f};
        #pragma unroll
        for (int p = 0; p < 8; ++p) {
            a0 += h2[p] * w[0][p];
            a1 += h2[p] * w[1][p];
            a2 += h2[p] * w[2][p];
            a3 += h2[p] * w[3][p];
        }
        const float vi = a0.x + a0.y, vf = a1.x + a1.y;
        const float vg = a2.x + a2.y, vo = a3.x + a3.y;

        const float ig = __builtin_amdgcn_rcpf(1.f + __builtin_amdgcn_exp2f(vi * NL2E));
        const float fg = __builtin_amdgcn_rcpf(1.f + __builtin_amdgcn_exp2f(vf * NL2E));
        const float gg = 2.f * __builtin_amdgcn_rcpf(1.f + __builtin_amdgcn_exp2f(vg * NL2E2)) - 1.f;
        const float og = __builtin_amdgcn_rcpf(1.f + __builtin_amdgcn_exp2f(vo * NL2E));

        c = fg * c + ig * gg;
        const float tc = 2.f * __builtin_amdgcn_rcpf(1.f + __builtin_amdgcn_exp2f(c * NL2E2)) - 1.f;
        const float hv = og * tc;

        hx[lb][j] = hv;
        const float4 b0 = hp[0], b1 = hp[1], b2 = hp[2], b3 = hp[3];
        h2[0] = (v2f){b0.x, b0.y}; h2[1] = (v2f){b0.z, b0.w};
        h2[2] = (v2f){b1.x, b1.y}; h2[3] = (v2f){b1.z, b1.w};
        h2[4] = (v2f){b2.x, b2.y}; h2[5] = (v2f){b2.z, b2.w};
        h2[6] = (v2f){b3.x, b3.y}; h2[7] = (v2f){b3.z, b3.w};

        idx_n = idx_nn;
    }

    if (j == 0) {
        float logit = bfc[0];
        #pragma unroll
        for (int p = 0; p < 8; ++p)
            logit += h2[p].x * Wfc[2 * p] + h2[p].y * Wfc[2 * p + 1];
        out[batch] = __builtin_amdgcn_rcpf(1.f + __builtin_amdgcn_exp2f(logit * NL2E));
    }
}

extern "C" void kernel_launch(void* const* d_in, const int* in_sizes, int n_in,
                              void* d_out, int out_size, void* d_ws, size_t ws_size,
                              hipStream_t stream) {
    const int*   x   = (const int*)  d_in[0];
    const float* emb = (const float*)d_in[1];
    const float* Wih = (const float*)d_in[2];
    const float* Whh = (const float*)d_in[3];
    const float* bih = (const float*)d_in[4];
    const float* bhh = (const float*)d_in[5];
    const float* Wfc = (const float*)d_in[6];
    const float* bfc = (const float*)d_in[7];
    float* outp = (float*)d_out;

    const int B = in_sizes[0] / T_LEN;                               // 4096
    const size_t TABLE_BYTES = (size_t)VOCAB1 * 64 * sizeof(float);  // 12.8 MB

    if (ws_size >= TABLE_BYTES) {
        float* tbl = (float*)d_ws;
        build_table<<<(VOCAB1 * 16 + 255) / 256, 256, 0, stream>>>(emb, Wih, bih, bhh, tbl);
        lstm_ilp2p_kernel<<<B / 8, 64, 0, stream>>>(x, tbl, Whh, Wfc, bfc, outp);
    } else {
        lstm_fb_kernel<<<B / 16, 256, 0, stream>>>(x, emb, Wih, Whh, bih, bhh, Wfc, bfc, outp);
    }
}